// Round 6
// baseline (2151.617 us; speedup 1.0000x reference)
//
#include <hip/hip_runtime.h>
#include <hip/hip_bf16.h>
#include <math.h>

// ---------------------------------------------------------------------------
// SelfInteractionUNet on MI355X — round 5 (round-4 design, syntax fixed).
// Round-3 counters: VALUBusy 34% vs MfmaUtil 15% -> A-generation VALU-bound
// (rounded split ~10 ops/elem, duplicated y=4) + 176MB overfetch.
// Fixes: (1) truncation hi/lo split (~3 ops/elem, residual exact in lo);
// (2) ALL operands stored pre-split hi/lo bf16 (state/s2/v2/h) -> h/g-gemm
//     A-staging and seg0 copies are pure LDS copies, no gen VALU;
// (3) 32x256 tiles (y=1, no A duplication), K-step 32, 46KB LDS -> 3 blk/CU,
//     s2+v2 fused in one dispatch via z (2048 blocks).
// Numerics: split-bf16 3-term MFMA (Ah*Bh + Al*Bh + Ah*Bl), fp32 accum,
// state hi/lo lives in d_out (16NM bytes exact), ws = 237.0 MB (proven fit).
// ---------------------------------------------------------------------------

typedef __attribute__((ext_vector_type(8))) short bf16x8;
typedef __attribute__((ext_vector_type(4))) short bf16x4;
typedef __attribute__((ext_vector_type(4))) float f32x4;
typedef __attribute__((ext_vector_type(4))) _Float16 f16x4;

__device__ __forceinline__ unsigned asu(float f){ union{float f;unsigned u;}x; x.f=f; return x.u; }
__device__ __forceinline__ float asf(unsigned u){ union{unsigned u;float f;}x; x.u=u; return x.f; }

// rounded bf16 (one-time prep kernels only)
__device__ __forceinline__ unsigned short f2bf_r(float f){
  unsigned i = asu(f);
  return (unsigned short)((i + 0x7fffu + ((i >> 16) & 1u)) >> 16);
}
__device__ __forceinline__ float bf2f(unsigned short u){ return asf(((unsigned)u) << 16); }

// truncation split: f = hi + lo with hi,lo bf16; lo captures hi's trunc error
__device__ __forceinline__ void split_t(float f, short& hi, short& lo){
  unsigned u = asu(f);
  hi = (short)(u >> 16);
  float lof = f - asf(u & 0xffff0000u);
  lo = (short)(asu(lof) >> 16);
}
// reconstruct fp32 from hi/lo pair
__device__ __forceinline__ float rec(short h, short l){
  return asf(((unsigned)(unsigned short)h) << 16) + asf(((unsigned)(unsigned short)l) << 16);
}
__device__ __forceinline__ f32x4 rec4(const unsigned short* H, const unsigned short* L, size_t o){
  bf16x4 hv = *(const bf16x4*)(H + o);
  bf16x4 lv = *(const bf16x4*)(L + o);
  f32x4 f;
  #pragma unroll
  for (int j = 0; j < 4; ++j) f[j] = rec(hv[j], lv[j]);
  return f;
}

// ---------------------------------------------------------------------------
// Weight transpose + fp32 -> split bf16 (rounded): W[9][K][Mo] -> Wh/Wl[9][Mo][K]
// ---------------------------------------------------------------------------
__global__ __launch_bounds__(256)
void transpose_w(const float* __restrict__ W, unsigned short* __restrict__ Wh,
                 unsigned short* __restrict__ Wl, int K, int Mo){
  __shared__ float tile[32][33];
  const int bi = blockIdx.z;
  const float* Wb = W + (size_t)bi * K * Mo;
  const size_t wo = (size_t)bi * K * Mo;
  const int k0 = blockIdx.x * 32, o0 = blockIdx.y * 32;
  const int tx = threadIdx.x & 31, ty = threadIdx.x >> 5;
  #pragma unroll
  for (int i = 0; i < 4; ++i){
    int k = ty + i * 8;
    tile[k][tx] = Wb[(size_t)(k0 + k) * Mo + o0 + tx];
  }
  __syncthreads();
  #pragma unroll
  for (int i = 0; i < 4; ++i){
    int o = ty + i * 8;
    float f = tile[tx][o];
    unsigned short h = f2bf_r(f);
    unsigned short l = f2bf_r(f - bf2f(h));
    Wh[wo + (size_t)(o0 + o) * K + k0 + tx] = h;
    Wl[wo + (size_t)(o0 + o) * K + k0 + tx] = l;
  }
}

// ---------------------------------------------------------------------------
// Inputs fp32 -> hi/lo bf16 state planes (in d_out).
// ---------------------------------------------------------------------------
__global__ __launch_bounds__(256)
void convert_inputs(const float* __restrict__ s, const float* __restrict__ v,
                    unsigned short* __restrict__ stH, unsigned short* __restrict__ stL,
                    int NM){
  int i = blockIdx.x * 256 + threadIdx.x;
  if (i >= NM) return;
  short h, l;
  split_t(s[i], h, l); stH[i] = h; stL[i] = l;
  const float* vp = v + (size_t)i * 3;
  #pragma unroll
  for (int d = 0; d < 3; ++d){
    split_t(vp[d], h, l);
    stH[(size_t)(1 + d) * NM + i] = h;
    stL[(size_t)(1 + d) * NM + i] = l;
  }
}

// ---------------------------------------------------------------------------
// Fused s2/v2 GEMM. z=0: s2 = s_in@W0 (K=768); z=1..3: v2_d = v_in_d@W1 (K=512).
// Tile 32 rows x 256 cols (y=1), 4 waves (col strips of 64), K-step 32.
// A generated on the fly from hi/lo state planes (+optional fp16 skip),
// truncation-split into LDS. 3-term split MFMA.
// ---------------------------------------------------------------------------
__global__ __launch_bounds__(256, 3)
void gemm_sv(const unsigned short* __restrict__ StH, const unsigned short* __restrict__ StL,
             const _Float16* __restrict__ skip,
             const unsigned short* __restrict__ W0h, const unsigned short* __restrict__ W0l,
             const unsigned short* __restrict__ W1h, const unsigned short* __restrict__ W1l,
             unsigned short* __restrict__ s2H, unsigned short* __restrict__ s2L,
             unsigned short* __restrict__ v2H, unsigned short* __restrict__ v2L,
             int NM, float cs, float cv)
{
  __shared__ unsigned short Ah[32][40], Al[32][40];
  __shared__ unsigned short Bhs[256][40], Bls[256][40];
  const int tid  = threadIdx.x;
  const int lane = tid & 63;
  const int wave = tid >> 6;
  const int wn   = wave * 64;
  const int row0 = blockIdx.x * 32;
  const int z    = blockIdx.z;
  const bool isS = (z == 0);
  const int dv   = z - 1;
  const int K    = isS ? 768 : 512;
  const float scale = isS ? cs : cv;
  const unsigned short* Bh = isS ? W0h : W1h;
  const unsigned short* Bl = isS ? W0l : W1l;
  unsigned short* outH = isS ? s2H : v2H + (size_t)dv * NM;
  unsigned short* outL = isS ? s2L : v2L + (size_t)dv * NM;
  const bool sk = (skip != nullptr);

  f32x4 acc[2][4];
  #pragma unroll
  for (int m = 0; m < 2; ++m)
    #pragma unroll
    for (int n = 0; n < 4; ++n) acc[m][n] = (f32x4){0.f,0.f,0.f,0.f};

  // A-stage indices (fixed per thread): 256 thr x 4 elems = 32x32 tile
  const int ar = tid >> 3;          // 0..31
  const int ac4 = (tid & 7) * 4;    // 0..28

  for (int k0 = 0; k0 < K; k0 += 32){
    const int seg = k0 >> 8;
    {
      const int gr = row0 + ar;
      const int c  = (k0 + ac4) & 255;
      const size_t o = (size_t)gr * 256 + c;
      if (!sk && seg == 0){
        // pure copy from pre-split plane
        const int p = isS ? 0 : 1 + dv;
        *(bf16x4*)(&Ah[ar][ac4]) = *(const bf16x4*)(StH + (size_t)p * NM + o);
        *(bf16x4*)(&Al[ar][ac4]) = *(const bf16x4*)(StL + (size_t)p * NM + o);
      } else {
        f32x4 f;
        if (isS){
          if (seg <= 1){
            f32x4 x = rec4(StH, StL, o);
            if (sk){
              f16x4 y = *(const f16x4*)(skip + o);
              #pragma unroll
              for (int j = 0; j < 4; ++j) x[j] += (float)y[j];
            }
            if (seg == 0){
              f = x;
            } else {
              #pragma unroll
              for (int j = 0; j < 4; ++j) f[j] = x[j]*x[j];
            }
          } else {
            f32x4 a0 = rec4(StH, StL, (size_t)NM + o);
            f32x4 a1 = rec4(StH, StL, (size_t)2*NM + o);
            f32x4 a2 = rec4(StH, StL, (size_t)3*NM + o);
            if (sk){
              f16x4 b0 = *(const f16x4*)(skip + (size_t)NM + o);
              f16x4 b1 = *(const f16x4*)(skip + (size_t)2*NM + o);
              f16x4 b2 = *(const f16x4*)(skip + (size_t)3*NM + o);
              #pragma unroll
              for (int j = 0; j < 4; ++j){ a0[j]+=(float)b0[j]; a1[j]+=(float)b1[j]; a2[j]+=(float)b2[j]; }
            }
            #pragma unroll
            for (int j = 0; j < 4; ++j)
              f[j] = (a0[j]*a0[j] + a1[j]*a1[j] + a2[j]*a2[j]) * 0.57735026918962576f;
          }
        } else {
          f32x4 x = rec4(StH, StL, (size_t)(1+dv)*NM + o);
          if (sk){
            f16x4 y = *(const f16x4*)(skip + (size_t)(1+dv)*NM + o);
            #pragma unroll
            for (int j = 0; j < 4; ++j) x[j] += (float)y[j];
          }
          if (seg == 0){
            f = x;
          } else {
            f32x4 s = rec4(StH, StL, o);
            if (sk){
              f16x4 y = *(const f16x4*)(skip + o);
              #pragma unroll
              for (int j = 0; j < 4; ++j) s[j] += (float)y[j];
            }
            #pragma unroll
            for (int j = 0; j < 4; ++j) f[j] = 1.41421356237309505f * s[j] * x[j];
          }
        }
        bf16x4 hi, lo;
        #pragma unroll
        for (int j = 0; j < 4; ++j){ short h, l; split_t(f[j], h, l); hi[j]=h; lo[j]=l; }
        *(bf16x4*)(&Ah[ar][ac4]) = hi;
        *(bf16x4*)(&Al[ar][ac4]) = lo;
      }
    }
    // B-stage: 256 cols x 32 k, hi/lo
    #pragma unroll
    for (int it = 0; it < 4; ++it){
      int idx = tid + it * 256;
      int br  = idx >> 2;
      int kc  = (idx & 3) * 8;
      const size_t o = (size_t)br * K + k0 + kc;
      *(bf16x8*)(&Bhs[br][kc]) = *(const bf16x8*)(Bh + o);
      *(bf16x8*)(&Bls[br][kc]) = *(const bf16x8*)(Bl + o);
    }
    __syncthreads();

    const int arow = lane & 15;
    const int kq   = (lane >> 4) * 8;
    bf16x8 ah[2], al[2], bh[4], bl[4];
    #pragma unroll
    for (int m = 0; m < 2; ++m){
      ah[m] = *(const bf16x8*)(&Ah[m*16 + arow][kq]);
      al[m] = *(const bf16x8*)(&Al[m*16 + arow][kq]);
    }
    #pragma unroll
    for (int n = 0; n < 4; ++n){
      bh[n] = *(const bf16x8*)(&Bhs[wn + n*16 + arow][kq]);
      bl[n] = *(const bf16x8*)(&Bls[wn + n*16 + arow][kq]);
    }
    #pragma unroll
    for (int m = 0; m < 2; ++m)
      #pragma unroll
      for (int n = 0; n < 4; ++n){
        acc[m][n] = __builtin_amdgcn_mfma_f32_16x16x32_bf16(ah[m], bh[n], acc[m][n], 0, 0, 0);
        acc[m][n] = __builtin_amdgcn_mfma_f32_16x16x32_bf16(al[m], bh[n], acc[m][n], 0, 0, 0);
        acc[m][n] = __builtin_amdgcn_mfma_f32_16x16x32_bf16(ah[m], bl[n], acc[m][n], 0, 0, 0);
      }
    __syncthreads();
  }

  // epilogue: split-store (C/D layout m89: col=lane&15, row=(lane>>4)*4+j)
  #pragma unroll
  for (int m = 0; m < 2; ++m){
    #pragma unroll
    for (int n = 0; n < 4; ++n){
      const int cg = wn + n * 16 + (lane & 15);
      #pragma unroll
      for (int j = 0; j < 4; ++j){
        const int rg = row0 + m * 16 + ((lane >> 4) * 4) + j;
        short h, l; split_t(acc[m][n][j] * scale, h, l);
        outH[(size_t)rg * 256 + cg] = (unsigned short)h;
        outL[(size_t)rg * 256 + cg] = (unsigned short)l;
      }
    }
  }
}

// ---------------------------------------------------------------------------
// h/g GEMM: A pre-split hi/lo [N][256] (pure copy staging), K=256.
// Tile 32 x 256 (col block = blockIdx.y*256), 4 waves, K-step 32.
// EPI: 1 = silu -> split store; 2 = gate -> split state; 3 = gate -> fp32 out
// ---------------------------------------------------------------------------
template<int EPI>
__global__ __launch_bounds__(256, 3)
void gemm_hg(const unsigned short* __restrict__ AhG, const unsigned short* __restrict__ AlG,
             const unsigned short* __restrict__ Bh, const unsigned short* __restrict__ Bl,
             int NM, float scale,
             unsigned short* __restrict__ outH, unsigned short* __restrict__ outL,
             const unsigned short* __restrict__ s2H, const unsigned short* __restrict__ s2L,
             const unsigned short* __restrict__ v2H, const unsigned short* __restrict__ v2L,
             unsigned short* __restrict__ stH, unsigned short* __restrict__ stL,
             float* __restrict__ fout)
{
  __shared__ unsigned short Ah[32][40], Al[32][40];
  __shared__ unsigned short Bhs[256][40], Bls[256][40];
  const int tid  = threadIdx.x;
  const int lane = tid & 63;
  const int wave = tid >> 6;
  const int wn   = wave * 64;
  const int row0 = blockIdx.x * 32;
  const int col0 = blockIdx.y * 256;
  const int K = 256;

  f32x4 acc[2][4];
  #pragma unroll
  for (int m = 0; m < 2; ++m)
    #pragma unroll
    for (int n = 0; n < 4; ++n) acc[m][n] = (f32x4){0.f,0.f,0.f,0.f};

  const int ar = tid >> 3;
  const int ac4 = (tid & 7) * 4;

  for (int k0 = 0; k0 < K; k0 += 32){
    {
      const size_t o = (size_t)(row0 + ar) * 256 + k0 + ac4;
      *(bf16x4*)(&Ah[ar][ac4]) = *(const bf16x4*)(AhG + o);
      *(bf16x4*)(&Al[ar][ac4]) = *(const bf16x4*)(AlG + o);
    }
    #pragma unroll
    for (int it = 0; it < 4; ++it){
      int idx = tid + it * 256;
      int br  = idx >> 2;
      int kc  = (idx & 3) * 8;
      const size_t o = (size_t)(col0 + br) * K + k0 + kc;
      *(bf16x8*)(&Bhs[br][kc]) = *(const bf16x8*)(Bh + o);
      *(bf16x8*)(&Bls[br][kc]) = *(const bf16x8*)(Bl + o);
    }
    __syncthreads();

    const int arow = lane & 15;
    const int kq   = (lane >> 4) * 8;
    bf16x8 ah[2], al[2], bh[4], bl[4];
    #pragma unroll
    for (int m = 0; m < 2; ++m){
      ah[m] = *(const bf16x8*)(&Ah[m*16 + arow][kq]);
      al[m] = *(const bf16x8*)(&Al[m*16 + arow][kq]);
    }
    #pragma unroll
    for (int n = 0; n < 4; ++n){
      bh[n] = *(const bf16x8*)(&Bhs[wn + n*16 + arow][kq]);
      bl[n] = *(const bf16x8*)(&Bls[wn + n*16 + arow][kq]);
    }
    #pragma unroll
    for (int m = 0; m < 2; ++m)
      #pragma unroll
      for (int n = 0; n < 4; ++n){
        acc[m][n] = __builtin_amdgcn_mfma_f32_16x16x32_bf16(ah[m], bh[n], acc[m][n], 0, 0, 0);
        acc[m][n] = __builtin_amdgcn_mfma_f32_16x16x32_bf16(al[m], bh[n], acc[m][n], 0, 0, 0);
        acc[m][n] = __builtin_amdgcn_mfma_f32_16x16x32_bf16(ah[m], bl[n], acc[m][n], 0, 0, 0);
      }
    __syncthreads();
  }

  #pragma unroll
  for (int m = 0; m < 2; ++m){
    #pragma unroll
    for (int n = 0; n < 4; ++n){
      const int cl = wn + n * 16 + (lane & 15);
      const int cg = col0 + cl;
      #pragma unroll
      for (int j = 0; j < 4; ++j){
        const int rg = row0 + m * 16 + ((lane >> 4) * 4) + j;
        float val = acc[m][n][j] * scale;
        if (EPI == 1){
          float sl = val / (1.f + expf(-val));
          short h, l; split_t(sl, h, l);
          outH[(size_t)rg * 256 + cg] = (unsigned short)h;
          outL[(size_t)rg * 256 + cg] = (unsigned short)l;
        } else {
          float gv = val / (1.f + expf(-val));
          if (cg < 256){
            const size_t o = (size_t)rg * 256 + cg;
            float sval = rec(s2H[o], s2L[o]) * gv;
            if (EPI == 2){
              short h, l; split_t(sval, h, l);
              stH[o] = (unsigned short)h; stL[o] = (unsigned short)l;
            } else {
              fout[(size_t)rg * 1024 + cg] = sval;
            }
          } else {
            const int c = cg - 256;
            #pragma unroll
            for (int d = 0; d < 3; ++d){
              const size_t o = (size_t)d * NM + (size_t)rg * 256 + c;
              float vv = rec(v2H[o], v2L[o]) * gv;
              if (EPI == 2){
                short h, l; split_t(vv, h, l);
                stH[(size_t)(1+d) * NM + (size_t)rg * 256 + c] = (unsigned short)h;
                stL[(size_t)(1+d) * NM + (size_t)rg * 256 + c] = (unsigned short)l;
              } else {
                fout[(size_t)rg * 1024 + 256 + 3 * (size_t)c + d] = vv;
              }
            }
          }
        }
      }
    }
  }
}

// ---------------------------------------------------------------------------
// Equivariant layernorm on hi/lo state; optional fp16 snapshot.
// ---------------------------------------------------------------------------
__global__ __launch_bounds__(256)
void ln_k(unsigned short* __restrict__ stH, unsigned short* __restrict__ stL,
          _Float16* __restrict__ snap, int NM){
  const int row  = blockIdx.x * 4 + (threadIdx.x >> 6);
  const int lane = threadIdx.x & 63;
  const size_t o = (size_t)row * 256 + lane * 4;
  f32x4 sv = rec4(stH, stL, o);
  f32x4 v0 = rec4(stH, stL, (size_t)NM + o);
  f32x4 v1 = rec4(stH, stL, (size_t)2*NM + o);
  f32x4 v2 = rec4(stH, stL, (size_t)3*NM + o);
  float r0 = 0.f, r1 = 0.f, r2 = 0.f;
  #pragma unroll
  for (int j = 0; j < 4; ++j){
    r0 += sv[j];
    r1 += sv[j] * sv[j];
    r2 += v0[j]*v0[j] + v1[j]*v1[j] + v2[j]*v2[j];
  }
  #pragma unroll
  for (int off = 1; off < 64; off <<= 1){
    r0 += __shfl_xor(r0, off, 64);
    r1 += __shfl_xor(r1, off, 64);
    r2 += __shfl_xor(r2, off, 64);
  }
  float mu  = r0 * (1.f / 256.f);
  float var = r1 * (1.f / 256.f) - mu * mu;
  float srs = rsqrtf(var + 1e-6f);
  float vrs = rsqrtf(r2 * (1.f / 768.f) + 1e-6f);
  f32x4 pl[4];
  #pragma unroll
  for (int j = 0; j < 4; ++j){
    pl[0][j] = (sv[j] - mu) * srs;
    pl[1][j] = v0[j] * vrs; pl[2][j] = v1[j] * vrs; pl[3][j] = v2[j] * vrs;
  }
  #pragma unroll
  for (int p = 0; p < 4; ++p){
    bf16x4 hv, lv; f16x4 hx;
    #pragma unroll
    for (int j = 0; j < 4; ++j){
      short h, l; split_t(pl[p][j], h, l);
      hv[j] = h; lv[j] = l; hx[j] = (_Float16)pl[p][j];
    }
    *(bf16x4*)(stH + (size_t)p*NM + o) = hv;
    *(bf16x4*)(stL + (size_t)p*NM + o) = lv;
    if (snap) *(f16x4*)(snap + (size_t)p*NM + o) = hx;
  }
}

// ---------------------------------------------------------------------------
extern "C" void kernel_launch(void* const* d_in, const int* in_sizes, int n_in,
                              void* d_out, int out_size, void* d_ws, size_t ws_size,
                              hipStream_t stream){
  const float* s_in = (const float*)d_in[0];
  const float* v_in = (const float*)d_in[1];
  const float* W0 = (const float*)d_in[2];   // [9][768][256]
  const float* W1 = (const float*)d_in[3];   // [9][512][256]
  const float* Wa = (const float*)d_in[4];   // [9][256][256]
  const float* Wb = (const float*)d_in[5];   // [9][256][512]
  const int Mdim = 256;
  const int N  = in_sizes[0] / Mdim;         // 16384
  const int NM = N * Mdim;

  unsigned short* ws = (unsigned short*)d_ws;
  size_t off = 0;
  auto alloc = [&](size_t elems){ unsigned short* p = ws + off; off += elems; return p; };
  unsigned short* W0h = alloc((size_t)9 * 768 * 256);
  unsigned short* W0l = alloc((size_t)9 * 768 * 256);
  unsigned short* W1h = alloc((size_t)9 * 512 * 256);
  unsigned short* W1l = alloc((size_t)9 * 512 * 256);
  unsigned short* Wah = alloc((size_t)9 * 256 * 256);
  unsigned short* Wal = alloc((size_t)9 * 256 * 256);
  unsigned short* Wbh = alloc((size_t)9 * 256 * 512);
  unsigned short* Wbl = alloc((size_t)9 * 256 * 512);
  unsigned short* s2H = alloc(NM);
  unsigned short* s2L = alloc(NM);
  unsigned short* v2H = alloc((size_t)3 * NM);
  unsigned short* v2L = alloc((size_t)3 * NM);
  unsigned short* hH  = alloc(NM);
  unsigned short* hL  = alloc(NM);
  _Float16* skips = (_Float16*)(ws + off);   // 16*NM fp16
  (void)ws_size;

  // state hi/lo planes live in d_out: 8 planes x NM x 2B = 16NM B = out bytes
  unsigned short* stateH = (unsigned short*)d_out;
  unsigned short* stateL = stateH + (size_t)4 * NM;

  dim3 blk(256);
  transpose_w<<<dim3(768/32, 256/32, 9), blk, 0, stream>>>(W0, W0h, W0l, 768, 256);
  transpose_w<<<dim3(512/32, 256/32, 9), blk, 0, stream>>>(W1, W1h, W1l, 512, 256);
  transpose_w<<<dim3(256/32, 256/32, 9), blk, 0, stream>>>(Wa, Wah, Wal, 256, 256);
  transpose_w<<<dim3(256/32, 512/32, 9), blk, 0, stream>>>(Wb, Wbh, Wbl, 256, 512);
  convert_inputs<<<dim3(NM/256), blk, 0, stream>>>(s_in, v_in, stateH, stateL, NM);

  const float c_s2 = 1.f / sqrtf(768.f);
  const float c_v2 = 1.f / sqrtf(512.f);
  const float c_hg = 1.f / 16.f;
  const int gx = N / 32;                     // 512 row blocks

  auto run_block = [&](int i, const _Float16* skip, bool fin){
    const unsigned short* w0h = W0h + (size_t)i * 768 * 256;
    const unsigned short* w0l = W0l + (size_t)i * 768 * 256;
    const unsigned short* w1h = W1h + (size_t)i * 512 * 256;
    const unsigned short* w1l = W1l + (size_t)i * 512 * 256;
    const unsigned short* wah = Wah + (size_t)i * 256 * 256;
    const unsigned short* wal = Wal + (size_t)i * 256 * 256;
    const unsigned short* wbh = Wbh + (size_t)i * 256 * 512;
    const unsigned short* wbl = Wbl + (size_t)i * 256 * 512;
    gemm_sv<<<dim3(gx, 1, 4), blk, 0, stream>>>(stateH, stateL, skip,
                                                w0h, w0l, w1h, w1l,
                                                s2H, s2L, v2H, v2L, NM, c_s2, c_v2);
    gemm_hg<1><<<dim3(gx, 1), blk, 0, stream>>>(s2H, s2L, wah, wal, NM, c_hg,
                                                hH, hL, nullptr, nullptr, nullptr, nullptr,
                                                nullptr, nullptr, nullptr);
    if (!fin)
      gemm_hg<2><<<dim3(gx, 2), blk, 0, stream>>>(hH, hL, wbh, wbl, NM, c_hg,
                                                  nullptr, nullptr, s2H, s2L, v2H, v2L,
                                                  stateH, stateL, nullptr);
    else
      gemm_hg<3><<<dim3(gx, 2), blk, 0, stream>>>(hH, hL, wbh, wbl, NM, c_hg,
                                                  nullptr, nullptr, s2H, s2L, v2H, v2L,
                                                  nullptr, nullptr, (float*)d_out);
  };

  for (int i = 0; i < 4; ++i){
    run_block(i, nullptr, false);
    ln_k<<<dim3(N/4), blk, 0, stream>>>(stateH, stateL, skips + (size_t)i * 4 * NM, NM);
  }
  run_block(4, nullptr, false);
  for (int j = 0; j < 4; ++j){
    run_block(5 + j, skips + (size_t)(3 - j) * 4 * NM, j == 3);
    if (j < 3) ln_k<<<dim3(N/4), blk, 0, stream>>>(stateH, stateL, nullptr, NM);
  }
}

// Round 7
// 2043.288 us; speedup vs baseline: 1.0530x; 1.0530x over previous
//
#include <hip/hip_runtime.h>
#include <hip/hip_bf16.h>
#include <math.h>

// ---------------------------------------------------------------------------
// SelfInteractionUNet on MI355X — round 6.
// Round-5 counters: nothing >30% busy; 32x256 tiles were staging-bound
// (B-LDS traffic 8:1 vs A) + 1.77e7 LDS bank conflicts (pitch-40 write
// conflicts). Fix: 128x128 tiles BK=64, 512 thr / 8 waves (wave 32x64),
// XOR-swizzled LDS (pitch 64, chunk^=row&7) -> conflict-free b128 r/w,
// 2 blk/CU. Numerics unchanged: pre-split hi/lo bf16 operands everywhere,
// 3-term split MFMA (Ah*Bh+Al*Bh+Ah*Bl), fp32 accum, truncation split.
// State hi/lo lives in d_out (16NM bytes exact). ws = 237 MB (proven fit).
// ---------------------------------------------------------------------------

typedef __attribute__((ext_vector_type(8))) short bf16x8;
typedef __attribute__((ext_vector_type(4))) short bf16x4;
typedef __attribute__((ext_vector_type(4))) float f32x4;
typedef __attribute__((ext_vector_type(4))) _Float16 f16x4;

__device__ __forceinline__ unsigned asu(float f){ union{float f;unsigned u;}x; x.f=f; return x.u; }
__device__ __forceinline__ float asf(unsigned u){ union{unsigned u;float f;}x; x.u=u; return x.f; }

__device__ __forceinline__ unsigned short f2bf_r(float f){
  unsigned i = asu(f);
  return (unsigned short)((i + 0x7fffu + ((i >> 16) & 1u)) >> 16);
}
__device__ __forceinline__ float bf2f(unsigned short u){ return asf(((unsigned)u) << 16); }

// truncation split: f = hi + lo, both bf16
__device__ __forceinline__ void split_t(float f, short& hi, short& lo){
  unsigned u = asu(f);
  hi = (short)(u >> 16);
  float lof = f - asf(u & 0xffff0000u);
  lo = (short)(asu(lof) >> 16);
}
__device__ __forceinline__ float rec(short h, short l){
  return asf(((unsigned)(unsigned short)h) << 16) + asf(((unsigned)(unsigned short)l) << 16);
}
__device__ __forceinline__ f32x4 rec4(const unsigned short* H, const unsigned short* L, size_t o){
  bf16x4 hv = *(const bf16x4*)(H + o);
  bf16x4 lv = *(const bf16x4*)(L + o);
  f32x4 f;
  #pragma unroll
  for (int j = 0; j < 4; ++j) f[j] = rec(hv[j], lv[j]);
  return f;
}

// swizzled LDS offset (shorts). pitch 64, 16B chunks XOR'd by row&7.
__device__ __forceinline__ int LO(int r, int kc){
  return r * 64 + ((((kc >> 3) ^ (r & 7)) << 3) | (kc & 7));
}

// ---------------------------------------------------------------------------
__global__ __launch_bounds__(256)
void transpose_w(const float* __restrict__ W, unsigned short* __restrict__ Wh,
                 unsigned short* __restrict__ Wl, int K, int Mo){
  __shared__ float tile[32][33];
  const int bi = blockIdx.z;
  const float* Wb = W + (size_t)bi * K * Mo;
  const size_t wo = (size_t)bi * K * Mo;
  const int k0 = blockIdx.x * 32, o0 = blockIdx.y * 32;
  const int tx = threadIdx.x & 31, ty = threadIdx.x >> 5;
  #pragma unroll
  for (int i = 0; i < 4; ++i){
    int k = ty + i * 8;
    tile[k][tx] = Wb[(size_t)(k0 + k) * Mo + o0 + tx];
  }
  __syncthreads();
  #pragma unroll
  for (int i = 0; i < 4; ++i){
    int o = ty + i * 8;
    float f = tile[tx][o];
    unsigned short h = f2bf_r(f);
    unsigned short l = f2bf_r(f - bf2f(h));
    Wh[wo + (size_t)(o0 + o) * K + k0 + tx] = h;
    Wl[wo + (size_t)(o0 + o) * K + k0 + tx] = l;
  }
}

__global__ __launch_bounds__(256)
void convert_inputs(const float* __restrict__ s, const float* __restrict__ v,
                    unsigned short* __restrict__ stH, unsigned short* __restrict__ stL,
                    int NM){
  int i = blockIdx.x * 256 + threadIdx.x;
  if (i >= NM) return;
  short h, l;
  split_t(s[i], h, l); stH[i] = h; stL[i] = l;
  const float* vp = v + (size_t)i * 3;
  #pragma unroll
  for (int d = 0; d < 3; ++d){
    split_t(vp[d], h, l);
    stH[(size_t)(1 + d) * NM + i] = h;
    stL[(size_t)(1 + d) * NM + i] = l;
  }
}

// ---------------------------------------------------------------------------
// Fused s2/v2 GEMM. Grid (N/128, 8). z=0,1: s2 col-halves (K=768);
// z=2..7: v2 plane (z-2)>>1, col-half (z-2)&1 (K=512).
// 128x128 tile, BK=64, 512 thr, 8 waves of 32x64. 3-term split MFMA.
// ---------------------------------------------------------------------------
__global__ __launch_bounds__(512, 4)
void gemm_sv(const unsigned short* __restrict__ StH, const unsigned short* __restrict__ StL,
             const _Float16* __restrict__ skip,
             const unsigned short* __restrict__ W0h, const unsigned short* __restrict__ W0l,
             const unsigned short* __restrict__ W1h, const unsigned short* __restrict__ W1l,
             unsigned short* __restrict__ s2H, unsigned short* __restrict__ s2L,
             unsigned short* __restrict__ v2H, unsigned short* __restrict__ v2L,
             int NM, float cs, float cv)
{
  __shared__ unsigned short Ash[128*64], Asl[128*64], Bsh[128*64], Bsl[128*64];
  const int tid = threadIdx.x;
  const int lane = tid & 63, wave = tid >> 6;
  const int wm = (wave >> 1) * 32, wn = (wave & 1) * 64;
  const int row0 = blockIdx.x * 128;
  const int z = blockIdx.y;
  const bool isS = (z < 2);
  const int dv = (z - 2) >> 1;
  const int col0 = isS ? z * 128 : ((z - 2) & 1) * 128;
  const int K = isS ? 768 : 512;
  const float scale = isS ? cs : cv;
  const unsigned short* Bhg = isS ? W0h : W1h;
  const unsigned short* Blg = isS ? W0l : W1l;
  unsigned short* outH = isS ? s2H : v2H + (size_t)dv * NM;
  unsigned short* outL = isS ? s2L : v2L + (size_t)dv * NM;
  const bool sk = (skip != nullptr);

  f32x4 acc[2][4];
  #pragma unroll
  for (int m = 0; m < 2; ++m){
    #pragma unroll
    for (int n = 0; n < 4; ++n) acc[m][n] = (f32x4){0.f,0.f,0.f,0.f};
  }

  const int bc = tid >> 2, bk = (tid & 3) * 16;   // B: col, k-offset
  const int arr = bc, akc = bk;                   // A: same mapping

  for (int k0 = 0; k0 < K; k0 += 64){
    // ---- B stage (2 chunks hi + 2 lo, coalesced 32B/thread)
    {
      const size_t o = (size_t)(col0 + bc) * K + k0 + bk;
      bf16x8 x0 = *(const bf16x8*)(Bhg + o);
      bf16x8 x1 = *(const bf16x8*)(Bhg + o + 8);
      bf16x8 y0 = *(const bf16x8*)(Blg + o);
      bf16x8 y1 = *(const bf16x8*)(Blg + o + 8);
      *(bf16x8*)(&Bsh[LO(bc, bk)])     = x0;
      *(bf16x8*)(&Bsh[LO(bc, bk + 8)]) = x1;
      *(bf16x8*)(&Bsl[LO(bc, bk)])     = y0;
      *(bf16x8*)(&Bsl[LO(bc, bk + 8)]) = y1;
    }
    // ---- A stage
    {
      const int gr = row0 + arr;
      const int c  = (k0 + akc) & 255;
      const size_t o = (size_t)gr * 256 + c;
      const int seg = k0 >> 8;
      if (!sk && seg == 0){
        const int p = isS ? 0 : 1 + dv;
        const unsigned short* SH = StH + (size_t)p * NM;
        const unsigned short* SL = StL + (size_t)p * NM;
        *(bf16x8*)(&Ash[LO(arr, akc)])     = *(const bf16x8*)(SH + o);
        *(bf16x8*)(&Ash[LO(arr, akc + 8)]) = *(const bf16x8*)(SH + o + 8);
        *(bf16x8*)(&Asl[LO(arr, akc)])     = *(const bf16x8*)(SL + o);
        *(bf16x8*)(&Asl[LO(arr, akc + 8)]) = *(const bf16x8*)(SL + o + 8);
      } else {
        f32x4 f[4];
        if (isS){
          if (seg <= 1){
            #pragma unroll
            for (int q = 0; q < 4; ++q){
              f32x4 x = rec4(StH, StL, o + 4*q);
              if (sk){
                f16x4 y = *(const f16x4*)(skip + o + 4*q);
                #pragma unroll
                for (int j = 0; j < 4; ++j) x[j] += (float)y[j];
              }
              if (seg == 0){
                f[q] = x;
              } else {
                #pragma unroll
                for (int j = 0; j < 4; ++j) f[q][j] = x[j] * x[j];
              }
            }
          } else {
            #pragma unroll
            for (int q = 0; q < 4; ++q){
              f32x4 a0 = rec4(StH, StL, (size_t)NM + o + 4*q);
              f32x4 a1 = rec4(StH, StL, (size_t)2*NM + o + 4*q);
              f32x4 a2 = rec4(StH, StL, (size_t)3*NM + o + 4*q);
              if (sk){
                f16x4 b0 = *(const f16x4*)(skip + (size_t)NM + o + 4*q);
                f16x4 b1 = *(const f16x4*)(skip + (size_t)2*NM + o + 4*q);
                f16x4 b2 = *(const f16x4*)(skip + (size_t)3*NM + o + 4*q);
                #pragma unroll
                for (int j = 0; j < 4; ++j){
                  a0[j] += (float)b0[j]; a1[j] += (float)b1[j]; a2[j] += (float)b2[j];
                }
              }
              #pragma unroll
              for (int j = 0; j < 4; ++j)
                f[q][j] = (a0[j]*a0[j] + a1[j]*a1[j] + a2[j]*a2[j]) * 0.57735026918962576f;
            }
          }
        } else {
          #pragma unroll
          for (int q = 0; q < 4; ++q){
            f32x4 x = rec4(StH, StL, (size_t)(1 + dv)*NM + o + 4*q);
            if (sk){
              f16x4 y = *(const f16x4*)(skip + (size_t)(1 + dv)*NM + o + 4*q);
              #pragma unroll
              for (int j = 0; j < 4; ++j) x[j] += (float)y[j];
            }
            if (seg == 0){
              f[q] = x;
            } else {
              f32x4 s = rec4(StH, StL, o + 4*q);
              if (sk){
                f16x4 y = *(const f16x4*)(skip + o + 4*q);
                #pragma unroll
                for (int j = 0; j < 4; ++j) s[j] += (float)y[j];
              }
              #pragma unroll
              for (int j = 0; j < 4; ++j) f[q][j] = 1.41421356237309505f * s[j] * x[j];
            }
          }
        }
        #pragma unroll
        for (int q = 0; q < 2; ++q){
          bf16x8 hi, lo;
          #pragma unroll
          for (int j = 0; j < 8; ++j){
            short h, l; split_t(f[q*2 + (j >> 2)][j & 3], h, l);
            hi[j] = h; lo[j] = l;
          }
          *(bf16x8*)(&Ash[LO(arr, akc + q*8)]) = hi;
          *(bf16x8*)(&Asl[LO(arr, akc + q*8)]) = lo;
        }
      }
    }
    __syncthreads();

    const int arow = lane & 15;
    const int ksl  = (lane >> 4) * 8;
    #pragma unroll
    for (int ks = 0; ks < 2; ++ks){
      const int kq = ks * 32 + ksl;
      bf16x8 ah[2], al[2], bh[4], bl[4];
      #pragma unroll
      for (int m = 0; m < 2; ++m){
        const int r = wm + m*16 + arow;
        ah[m] = *(const bf16x8*)(&Ash[LO(r, kq)]);
        al[m] = *(const bf16x8*)(&Asl[LO(r, kq)]);
      }
      #pragma unroll
      for (int n = 0; n < 4; ++n){
        const int r = wn + n*16 + arow;
        bh[n] = *(const bf16x8*)(&Bsh[LO(r, kq)]);
        bl[n] = *(const bf16x8*)(&Bsl[LO(r, kq)]);
      }
      #pragma unroll
      for (int m = 0; m < 2; ++m){
        #pragma unroll
        for (int n = 0; n < 4; ++n){
          acc[m][n] = __builtin_amdgcn_mfma_f32_16x16x32_bf16(ah[m], bh[n], acc[m][n], 0, 0, 0);
          acc[m][n] = __builtin_amdgcn_mfma_f32_16x16x32_bf16(al[m], bh[n], acc[m][n], 0, 0, 0);
          acc[m][n] = __builtin_amdgcn_mfma_f32_16x16x32_bf16(ah[m], bl[n], acc[m][n], 0, 0, 0);
        }
      }
    }
    __syncthreads();
  }

  // epilogue: C/D m89: col=lane&15, row=(lane>>4)*4+j
  #pragma unroll
  for (int m = 0; m < 2; ++m){
    #pragma unroll
    for (int n = 0; n < 4; ++n){
      const int cg = col0 + wn + n*16 + (lane & 15);
      #pragma unroll
      for (int j = 0; j < 4; ++j){
        const int rg = row0 + wm + m*16 + ((lane >> 4) * 4) + j;
        short h, l; split_t(acc[m][n][j] * scale, h, l);
        outH[(size_t)rg * 256 + cg] = (unsigned short)h;
        outL[(size_t)rg * 256 + cg] = (unsigned short)l;
      }
    }
  }
}

// ---------------------------------------------------------------------------
// h/g GEMM: A pre-split hi/lo [N][256], K=256. Grid (N/128, Mo/128).
// EPI: 1 = silu split-store; 2 = gate -> state; 3 = gate -> fp32 out
// ---------------------------------------------------------------------------
template<int EPI>
__global__ __launch_bounds__(512, 4)
void gemm_hg(const unsigned short* __restrict__ AhG, const unsigned short* __restrict__ AlG,
             const unsigned short* __restrict__ Bh, const unsigned short* __restrict__ Bl,
             int NM, float scale,
             unsigned short* __restrict__ outH, unsigned short* __restrict__ outL,
             const unsigned short* __restrict__ s2H, const unsigned short* __restrict__ s2L,
             const unsigned short* __restrict__ v2H, const unsigned short* __restrict__ v2L,
             unsigned short* __restrict__ stH, unsigned short* __restrict__ stL,
             float* __restrict__ fout)
{
  __shared__ unsigned short Ash[128*64], Asl[128*64], Bsh[128*64], Bsl[128*64];
  const int tid = threadIdx.x;
  const int lane = tid & 63, wave = tid >> 6;
  const int wm = (wave >> 1) * 32, wn = (wave & 1) * 64;
  const int row0 = blockIdx.x * 128;
  const int col0 = blockIdx.y * 128;
  const int K = 256;

  f32x4 acc[2][4];
  #pragma unroll
  for (int m = 0; m < 2; ++m){
    #pragma unroll
    for (int n = 0; n < 4; ++n) acc[m][n] = (f32x4){0.f,0.f,0.f,0.f};
  }

  const int bc = tid >> 2, bk = (tid & 3) * 16;

  for (int k0 = 0; k0 < K; k0 += 64){
    {
      const size_t o = (size_t)(col0 + bc) * K + k0 + bk;
      bf16x8 x0 = *(const bf16x8*)(Bh + o);
      bf16x8 x1 = *(const bf16x8*)(Bh + o + 8);
      bf16x8 y0 = *(const bf16x8*)(Bl + o);
      bf16x8 y1 = *(const bf16x8*)(Bl + o + 8);
      *(bf16x8*)(&Bsh[LO(bc, bk)])     = x0;
      *(bf16x8*)(&Bsh[LO(bc, bk + 8)]) = x1;
      *(bf16x8*)(&Bsl[LO(bc, bk)])     = y0;
      *(bf16x8*)(&Bsl[LO(bc, bk + 8)]) = y1;
    }
    {
      const size_t o = (size_t)(row0 + bc) * 256 + k0 + bk;
      *(bf16x8*)(&Ash[LO(bc, bk)])     = *(const bf16x8*)(AhG + o);
      *(bf16x8*)(&Ash[LO(bc, bk + 8)]) = *(const bf16x8*)(AhG + o + 8);
      *(bf16x8*)(&Asl[LO(bc, bk)])     = *(const bf16x8*)(AlG + o);
      *(bf16x8*)(&Asl[LO(bc, bk + 8)]) = *(const bf16x8*)(AlG + o + 8);
    }
    __syncthreads();

    const int arow = lane & 15;
    const int ksl  = (lane >> 4) * 8;
    #pragma unroll
    for (int ks = 0; ks < 2; ++ks){
      const int kq = ks * 32 + ksl;
      bf16x8 ah[2], al[2], bh[4], bl[4];
      #pragma unroll
      for (int m = 0; m < 2; ++m){
        const int r = wm + m*16 + arow;
        ah[m] = *(const bf16x8*)(&Ash[LO(r, kq)]);
        al[m] = *(const bf16x8*)(&Asl[LO(r, kq)]);
      }
      #pragma unroll
      for (int n = 0; n < 4; ++n){
        const int r = wn + n*16 + arow;
        bh[n] = *(const bf16x8*)(&Bsh[LO(r, kq)]);
        bl[n] = *(const bf16x8*)(&Bsl[LO(r, kq)]);
      }
      #pragma unroll
      for (int m = 0; m < 2; ++m){
        #pragma unroll
        for (int n = 0; n < 4; ++n){
          acc[m][n] = __builtin_amdgcn_mfma_f32_16x16x32_bf16(ah[m], bh[n], acc[m][n], 0, 0, 0);
          acc[m][n] = __builtin_amdgcn_mfma_f32_16x16x32_bf16(al[m], bh[n], acc[m][n], 0, 0, 0);
          acc[m][n] = __builtin_amdgcn_mfma_f32_16x16x32_bf16(ah[m], bl[n], acc[m][n], 0, 0, 0);
        }
      }
    }
    __syncthreads();
  }

  #pragma unroll
  for (int m = 0; m < 2; ++m){
    #pragma unroll
    for (int n = 0; n < 4; ++n){
      const int cg = col0 + wn + n*16 + (lane & 15);
      #pragma unroll
      for (int j = 0; j < 4; ++j){
        const int rg = row0 + wm + m*16 + ((lane >> 4) * 4) + j;
        float val = acc[m][n][j] * scale;
        if (EPI == 1){
          float sl = val / (1.f + expf(-val));
          short h, l; split_t(sl, h, l);
          outH[(size_t)rg * 256 + cg] = (unsigned short)h;
          outL[(size_t)rg * 256 + cg] = (unsigned short)l;
        } else {
          float gv = val / (1.f + expf(-val));
          if (cg < 256){
            const size_t o = (size_t)rg * 256 + cg;
            float sval = rec(s2H[o], s2L[o]) * gv;
            if (EPI == 2){
              short h, l; split_t(sval, h, l);
              stH[o] = (unsigned short)h; stL[o] = (unsigned short)l;
            } else {
              fout[(size_t)rg * 1024 + cg] = sval;
            }
          } else {
            const int c = cg - 256;
            #pragma unroll
            for (int d = 0; d < 3; ++d){
              const size_t o = (size_t)d * NM + (size_t)rg * 256 + c;
              float vv = rec(v2H[o], v2L[o]) * gv;
              if (EPI == 2){
                short h, l; split_t(vv, h, l);
                stH[(size_t)(1+d) * NM + (size_t)rg * 256 + c] = (unsigned short)h;
                stL[(size_t)(1+d) * NM + (size_t)rg * 256 + c] = (unsigned short)l;
              } else {
                fout[(size_t)rg * 1024 + 256 + 3 * (size_t)c + d] = vv;
              }
            }
          }
        }
      }
    }
  }
}

// ---------------------------------------------------------------------------
__global__ __launch_bounds__(256)
void ln_k(unsigned short* __restrict__ stH, unsigned short* __restrict__ stL,
          _Float16* __restrict__ snap, int NM){
  const int row  = blockIdx.x * 4 + (threadIdx.x >> 6);
  const int lane = threadIdx.x & 63;
  const size_t o = (size_t)row * 256 + lane * 4;
  f32x4 sv = rec4(stH, stL, o);
  f32x4 v0 = rec4(stH, stL, (size_t)NM + o);
  f32x4 v1 = rec4(stH, stL, (size_t)2*NM + o);
  f32x4 v2 = rec4(stH, stL, (size_t)3*NM + o);
  float r0 = 0.f, r1 = 0.f, r2 = 0.f;
  #pragma unroll
  for (int j = 0; j < 4; ++j){
    r0 += sv[j];
    r1 += sv[j] * sv[j];
    r2 += v0[j]*v0[j] + v1[j]*v1[j] + v2[j]*v2[j];
  }
  #pragma unroll
  for (int off = 1; off < 64; off <<= 1){
    r0 += __shfl_xor(r0, off, 64);
    r1 += __shfl_xor(r1, off, 64);
    r2 += __shfl_xor(r2, off, 64);
  }
  float mu  = r0 * (1.f / 256.f);
  float var = r1 * (1.f / 256.f) - mu * mu;
  float srs = rsqrtf(var + 1e-6f);
  float vrs = rsqrtf(r2 * (1.f / 768.f) + 1e-6f);
  f32x4 pl[4];
  #pragma unroll
  for (int j = 0; j < 4; ++j){
    pl[0][j] = (sv[j] - mu) * srs;
    pl[1][j] = v0[j] * vrs; pl[2][j] = v1[j] * vrs; pl[3][j] = v2[j] * vrs;
  }
  #pragma unroll
  for (int p = 0; p < 4; ++p){
    bf16x4 hv, lv; f16x4 hx;
    #pragma unroll
    for (int j = 0; j < 4; ++j){
      short h, l; split_t(pl[p][j], h, l);
      hv[j] = h; lv[j] = l; hx[j] = (_Float16)pl[p][j];
    }
    *(bf16x4*)(stH + (size_t)p*NM + o) = hv;
    *(bf16x4*)(stL + (size_t)p*NM + o) = lv;
    if (snap) *(f16x4*)(snap + (size_t)p*NM + o) = hx;
  }
}

// ---------------------------------------------------------------------------
extern "C" void kernel_launch(void* const* d_in, const int* in_sizes, int n_in,
                              void* d_out, int out_size, void* d_ws, size_t ws_size,
                              hipStream_t stream){
  const float* s_in = (const float*)d_in[0];
  const float* v_in = (const float*)d_in[1];
  const float* W0 = (const float*)d_in[2];   // [9][768][256]
  const float* W1 = (const float*)d_in[3];   // [9][512][256]
  const float* Wa = (const float*)d_in[4];   // [9][256][256]
  const float* Wb = (const float*)d_in[5];   // [9][256][512]
  const int Mdim = 256;
  const int N  = in_sizes[0] / Mdim;         // 16384
  const int NM = N * Mdim;

  unsigned short* ws = (unsigned short*)d_ws;
  size_t off = 0;
  auto alloc = [&](size_t elems){ unsigned short* p = ws + off; off += elems; return p; };
  unsigned short* W0h = alloc((size_t)9 * 768 * 256);
  unsigned short* W0l = alloc((size_t)9 * 768 * 256);
  unsigned short* W1h = alloc((size_t)9 * 512 * 256);
  unsigned short* W1l = alloc((size_t)9 * 512 * 256);
  unsigned short* Wah = alloc((size_t)9 * 256 * 256);
  unsigned short* Wal = alloc((size_t)9 * 256 * 256);
  unsigned short* Wbh = alloc((size_t)9 * 256 * 512);
  unsigned short* Wbl = alloc((size_t)9 * 256 * 512);
  unsigned short* s2H = alloc(NM);
  unsigned short* s2L = alloc(NM);
  unsigned short* v2H = alloc((size_t)3 * NM);
  unsigned short* v2L = alloc((size_t)3 * NM);
  unsigned short* hH  = alloc(NM);
  unsigned short* hL  = alloc(NM);
  _Float16* skips = (_Float16*)(ws + off);   // 16*NM fp16
  (void)ws_size;

  unsigned short* stateH = (unsigned short*)d_out;
  unsigned short* stateL = stateH + (size_t)4 * NM;

  dim3 blk(256);
  dim3 blk5(512);
  transpose_w<<<dim3(768/32, 256/32, 9), blk, 0, stream>>>(W0, W0h, W0l, 768, 256);
  transpose_w<<<dim3(512/32, 256/32, 9), blk, 0, stream>>>(W1, W1h, W1l, 512, 256);
  transpose_w<<<dim3(256/32, 256/32, 9), blk, 0, stream>>>(Wa, Wah, Wal, 256, 256);
  transpose_w<<<dim3(256/32, 512/32, 9), blk, 0, stream>>>(Wb, Wbh, Wbl, 256, 512);
  convert_inputs<<<dim3(NM/256), blk, 0, stream>>>(s_in, v_in, stateH, stateL, NM);

  const float c_s2 = 1.f / sqrtf(768.f);
  const float c_v2 = 1.f / sqrtf(512.f);
  const float c_hg = 1.f / 16.f;
  const int gx = N / 128;                    // 128 row blocks

  auto run_block = [&](int i, const _Float16* skip, bool fin){
    const unsigned short* w0h = W0h + (size_t)i * 768 * 256;
    const unsigned short* w0l = W0l + (size_t)i * 768 * 256;
    const unsigned short* w1h = W1h + (size_t)i * 512 * 256;
    const unsigned short* w1l = W1l + (size_t)i * 512 * 256;
    const unsigned short* wah = Wah + (size_t)i * 256 * 256;
    const unsigned short* wal = Wal + (size_t)i * 256 * 256;
    const unsigned short* wbh = Wbh + (size_t)i * 256 * 512;
    const unsigned short* wbl = Wbl + (size_t)i * 256 * 512;
    gemm_sv<<<dim3(gx, 8), blk5, 0, stream>>>(stateH, stateL, skip,
                                              w0h, w0l, w1h, w1l,
                                              s2H, s2L, v2H, v2L, NM, c_s2, c_v2);
    gemm_hg<1><<<dim3(gx, 2), blk5, 0, stream>>>(s2H, s2L, wah, wal, NM, c_hg,
                                                 hH, hL, nullptr, nullptr, nullptr, nullptr,
                                                 nullptr, nullptr, nullptr);
    if (!fin)
      gemm_hg<2><<<dim3(gx, 4), blk5, 0, stream>>>(hH, hL, wbh, wbl, NM, c_hg,
                                                   nullptr, nullptr, s2H, s2L, v2H, v2L,
                                                   stateH, stateL, nullptr);
    else
      gemm_hg<3><<<dim3(gx, 4), blk5, 0, stream>>>(hH, hL, wbh, wbl, NM, c_hg,
                                                   nullptr, nullptr, s2H, s2L, v2H, v2L,
                                                   nullptr, nullptr, (float*)d_out);
  };

  for (int i = 0; i < 4; ++i){
    run_block(i, nullptr, false);
    ln_k<<<dim3(N/4), blk, 0, stream>>>(stateH, stateL, skips + (size_t)i * 4 * NM, NM);
  }
  run_block(4, nullptr, false);
  for (int j = 0; j < 4; ++j){
    run_block(5 + j, skips + (size_t)(3 - j) * 4 * NM, j == 3);
    if (j < 3) ln_k<<<dim3(N/4), blk, 0, stream>>>(stateH, stateL, nullptr, NM);
  }
}